// Round 11
// baseline (221.113 us; speedup 1.0000x reference)
//
#include <hip/hip_runtime.h>
#include <hip/hip_bf16.h>
#include <hip/hip_fp8.h>

typedef __bf16 bf16;
typedef __bf16 v8bf __attribute__((ext_vector_type(8)));
typedef float v4f __attribute__((ext_vector_type(4)));
typedef float v2f __attribute__((ext_vector_type(2)));

#define NN 100000
#define NE 600000
#define HD 128
#define NG 256
#define NB 98                    // ceil(NN/1024)
#define NCHUNK ((NN + 63) / 64)  // 1563

#define PREP_CONV 6250
#define PREP_ZERO 391
#define PREP_BNDS 391
#define PREP_W 48
#define PREP_TOTAL (PREP_CONV + PREP_ZERO + PREP_BNDS + PREP_W)  // 7080

static __device__ inline v8bf zero8() {
    v8bf z;
#pragma unroll
    for (int i = 0; i < 8; ++i) z[i] = (bf16)0.f;
    return z;
}

// ---- OCP e4m3 helpers ----
static __device__ inline unsigned char enc_e4m3(float f) {
    __hip_fp8_e4m3 q(f);
    return (unsigned char)q.__x;
}

#if __has_builtin(__builtin_amdgcn_cvt_pk_fp8_f32)
static __device__ inline unsigned int pack4_e4m3(float v0, float v1, float v2, float v3) {
    int r = 0;
    r = __builtin_amdgcn_cvt_pk_fp8_f32(v0, v1, r, false);
    r = __builtin_amdgcn_cvt_pk_fp8_f32(v2, v3, r, true);
    return (unsigned int)r;
}
#else
static __device__ inline unsigned int pack4_e4m3(float v0, float v1, float v2, float v3) {
    return (unsigned int)enc_e4m3(v0) | ((unsigned int)enc_e4m3(v1) << 8) |
           ((unsigned int)enc_e4m3(v2) << 16) | ((unsigned int)enc_e4m3(v3) << 24);
}
#endif

#if __has_builtin(__builtin_amdgcn_cvt_pk_f32_fp8)
static __device__ inline void acc8(float* a, unsigned int lo, unsigned int hi) {
    v2f p0 = __builtin_amdgcn_cvt_pk_f32_fp8((int)lo, false);
    v2f p1 = __builtin_amdgcn_cvt_pk_f32_fp8((int)lo, true);
    v2f p2 = __builtin_amdgcn_cvt_pk_f32_fp8((int)hi, false);
    v2f p3 = __builtin_amdgcn_cvt_pk_f32_fp8((int)hi, true);
    a[0] += p0.x;
    a[1] += p0.y;
    a[2] += p1.x;
    a[3] += p1.y;
    a[4] += p2.x;
    a[5] += p2.y;
    a[6] += p3.x;
    a[7] += p3.y;
}
#else
static __device__ inline float dec_e4m3(unsigned int b) {
    unsigned int e = (b >> 3) & 15u, m = b & 7u;
    unsigned int s = (b & 0x80u) << 24;
    float nv = __uint_as_float(s | ((e + 120u) << 23) | (m << 20));
    float dv = __uint_as_float(s | 0x3B000000u) * (float)(int)m;
    return e ? nv : dv;
}
static __device__ inline void acc8(float* a, unsigned int lo, unsigned int hi) {
#pragma unroll
    for (int q = 0; q < 4; ++q) a[q] += dec_e4m3((lo >> (q * 8)) & 255u);
#pragma unroll
    for (int q = 0; q < 4; ++q) a[4 + q] += dec_e4m3((hi >> (q * 8)) & 255u);
}
#endif

static __device__ inline void acc16(float* a, uint4 r) {
    acc8(a, r.x, r.y);
    acc8(a + 8, r.z, r.w);
}

// ---- prep: conv(x->fp8) | zero cnt | graph bounds | weight prep (all 6) ----
__global__ void prep_kernel(const float* __restrict__ x, unsigned char* __restrict__ xb8,
                            int* __restrict__ cnt, const int* __restrict__ batch,
                            int* __restrict__ gstart, const float* __restrict__ w10,
                            const float* __restrict__ w20, const float* __restrict__ w11,
                            const float* __restrict__ w21, const float* __restrict__ w12,
                            const float* __restrict__ w22, bf16* __restrict__ Wt) {
    int bid = blockIdx.x, tid = threadIdx.x;
    if (bid < PREP_CONV) {
        int i = bid * 256 + tid;  // one per 8 elems
        const v4f a = *(const v4f*)&x[(size_t)i * 8];
        const v4f b = *(const v4f*)&x[(size_t)i * 8 + 4];
        unsigned int r0 = pack4_e4m3(a[0], a[1], a[2], a[3]);
        unsigned int r1 = pack4_e4m3(b[0], b[1], b[2], b[3]);
        *(uint2*)&xb8[(size_t)i * 8] = make_uint2(r0, r1);
    } else if (bid < PREP_CONV + PREP_ZERO) {
        int i = (bid - PREP_CONV) * 256 + tid;
        if (i < NN) cnt[i] = 0;
    } else if (bid < PREP_CONV + PREP_ZERO + PREP_BNDS) {
        int n = (bid - PREP_CONV - PREP_ZERO) * 256 + tid;
        if (n < NN) {
            int b = batch[n];
            int prev = (n == 0) ? -1 : batch[n - 1];
            for (int g = prev + 1; g <= b; ++g) gstart[g] = n;
            if (n == NN - 1)
                for (int g = b + 1; g <= NG; ++g) gstart[g] = NN;
        }
    } else {
        int wb = bid - (PREP_CONV + PREP_ZERO + PREP_BNDS);  // 0..47
        int widx = wb >> 3;
        const float* W;
        switch (widx) {
            case 0: W = w10; break;
            case 1: W = w20; break;
            case 2: W = w11; break;
            case 3: W = w21; break;
            case 4: W = w12; break;
            default: W = w22; break;
        }
        bf16* dst = Wt + (size_t)widx * 16384;
        int c = (wb & 7) * 256 + tid;  // 0..2047
        int j = c >> 4, ck = c & 15;
        v8bf o;
#pragma unroll
        for (int q = 0; q < 8; ++q) o[q] = (bf16)W[(ck * 8 + q) * 128 + j];
        *(v8bf*)&dst[j * 128 + ((ck ^ (j & 15)) << 3)] = o;
    }
}

// ---------------- CSR build (measured-good R6 chain) ----------------
__global__ void hist_kernel(const int* __restrict__ dst, int* __restrict__ cnt) {
    int e = blockIdx.x * blockDim.x + threadIdx.x;
    if (e < NE) atomicAdd(&cnt[dst[e]], 1);
}

__global__ void scan_part(const int* __restrict__ cnt, int* __restrict__ part) {
    __shared__ int red[256];
    int b = blockIdx.x, t = threadIdx.x;
    int base = b * 1024 + t * 4;
    int s = 0;
#pragma unroll
    for (int q = 0; q < 4; ++q) {
        int i = base + q;
        s += (i < NN) ? cnt[i] : 0;
    }
    red[t] = s;
    __syncthreads();
    for (int off = 128; off > 0; off >>= 1) {
        if (t < off) red[t] += red[t + off];
        __syncthreads();
    }
    if (t == 0) part[b] = red[0];
}

__global__ void scan_write(const int* __restrict__ cnt, const int* __restrict__ part,
                           int* __restrict__ rowStart, int* __restrict__ cursor) {
    __shared__ int tsum[256];
    __shared__ int psc[128];
    int b = blockIdx.x, t = threadIdx.x;
    if (t < 128) psc[t] = (t < NB) ? part[t] : 0;
    __syncthreads();
    for (int off = 1; off < 128; off <<= 1) {
        int v = (t < 128 && t >= off) ? psc[t - off] : 0;
        __syncthreads();
        if (t < 128) psc[t] += v;
        __syncthreads();
    }
    int blockoff = (b == 0) ? 0 : psc[b - 1];

    int base = b * 1024 + t * 4;
    int v[4];
    int s = 0;
#pragma unroll
    for (int q = 0; q < 4; ++q) {
        int i = base + q;
        v[q] = (i < NN) ? cnt[i] : 0;
        s += v[q];
    }
    tsum[t] = s;
    __syncthreads();
    for (int off = 1; off < 256; off <<= 1) {
        int x = (t >= off) ? tsum[t - off] : 0;
        __syncthreads();
        tsum[t] += x;
        __syncthreads();
    }
    int excl = tsum[t] - s + blockoff;
#pragma unroll
    for (int q = 0; q < 4; ++q) {
        int i = base + q;
        if (i < NN) {
            rowStart[i] = excl;
            cursor[i] = excl;
            excl += v[q];
        }
    }
    if (b == 0 && t == 0) rowStart[NN] = NE;
}

__global__ void scatter_kernel(const int* __restrict__ src, const int* __restrict__ dst,
                               int* __restrict__ cursor, int* __restrict__ sortedSrc) {
    int e = blockIdx.x * blockDim.x + threadIdx.x;
    if (e < NE) {
        int d = dst[e];
        int pos = atomicAdd(&cursor[d], 1);
        sortedSrc[pos] = src[e];
    }
}

// ------- aggregation from fp8: bufT = dec(h8[node]) + sum dec(h8[src]) -------
// 8 nodes per wave (8 lanes x 16B per row); 4-deep pipelined gather ->
// up to 32 row-fetches in flight per wave; HW cvt_pk decode.
__global__ __launch_bounds__(256) void agg_kernel(const unsigned char* __restrict__ h8,
                                                  const int* __restrict__ rowStart,
                                                  const int* __restrict__ sortedSrc,
                                                  bf16* __restrict__ hin) {
    int node = (blockIdx.x * blockDim.x + threadIdx.x) >> 3;
    if (node >= NN) return;
    int l8 = threadIdx.x & 7;
    int grp = (threadIdx.x & 63) >> 3;
    int s = rowStart[node], e = rowStart[node + 1];
    float a[16];
    uint4 self = *(const uint4*)&h8[(size_t)node * HD + l8 * 16];
#pragma unroll
    for (int q = 0; q < 16; ++q) a[q] = 0.f;
    acc16(a, self);
    for (int base = s; base < e; base += 8) {
        int cnt = e - base;
        if (cnt > 8) cnt = 8;
        int idx = (l8 < cnt) ? sortedSrc[base + l8] : 0;
        int i = 0;
        for (; i + 4 <= cnt; i += 4) {
            int sn0 = __shfl(idx, grp * 8 + i + 0, 64);
            int sn1 = __shfl(idx, grp * 8 + i + 1, 64);
            int sn2 = __shfl(idx, grp * 8 + i + 2, 64);
            int sn3 = __shfl(idx, grp * 8 + i + 3, 64);
            uint4 x0 = *(const uint4*)&h8[(size_t)sn0 * HD + l8 * 16];
            uint4 x1 = *(const uint4*)&h8[(size_t)sn1 * HD + l8 * 16];
            uint4 x2 = *(const uint4*)&h8[(size_t)sn2 * HD + l8 * 16];
            uint4 x3 = *(const uint4*)&h8[(size_t)sn3 * HD + l8 * 16];
            acc16(a, x0);
            acc16(a, x1);
            acc16(a, x2);
            acc16(a, x3);
        }
        for (; i + 2 <= cnt; i += 2) {
            int sn0 = __shfl(idx, grp * 8 + i + 0, 64);
            int sn1 = __shfl(idx, grp * 8 + i + 1, 64);
            uint4 x0 = *(const uint4*)&h8[(size_t)sn0 * HD + l8 * 16];
            uint4 x1 = *(const uint4*)&h8[(size_t)sn1 * HD + l8 * 16];
            acc16(a, x0);
            acc16(a, x1);
        }
        if (i < cnt) {
            int sn0 = __shfl(idx, grp * 8 + i, 64);
            uint4 x0 = *(const uint4*)&h8[(size_t)sn0 * HD + l8 * 16];
            acc16(a, x0);
        }
    }
    v8bf o0, o1;
#pragma unroll
    for (int q = 0; q < 8; ++q) {
        o0[q] = (bf16)a[q];
        o1[q] = (bf16)a[8 + q];
    }
    *(v8bf*)&hin[(size_t)node * HD + l8 * 16] = o0;
    *(v8bf*)&hin[(size_t)node * HD + l8 * 16 + 8] = o1;
}

// -------- fused MLP: persistent blocks, weights staged once in LDS --------
// fp8out=1 (layers 0,1): emit fp8 h_out via in-wave LDS byte-tile transpose.
// fp8out=0 (layer 2): emit bf16 h_out for pooling.
__global__ __launch_bounds__(256) void mlp_bf16(
    const bf16* __restrict__ hin, const bf16* __restrict__ W1s, const float* __restrict__ b1,
    const bf16* __restrict__ W2s, const float* __restrict__ b2, const float* __restrict__ gam,
    const float* __restrict__ bet, const int do_ln, const int fp8out,
    unsigned char* __restrict__ h8out, bf16* __restrict__ hout) {
    __shared__ bf16 lw[2][128 * 128];  // swizzled W1^T, W2^T (64KB)
    __shared__ bf16 lT[4][16 * 128];   // per-wave: relu tile, then fp8 byte-tile (16KB)

    const int tid = threadIdx.x;
    for (int i = tid; i < 2048; i += 256) {
        *(v8bf*)&lw[0][i * 8] = *(const v8bf*)&W1s[i * 8];
        *(v8bf*)&lw[1][i * 8] = *(const v8bf*)&W2s[i * 8];
    }
    __syncthreads();

    const int wave = tid >> 6, lane = tid & 63;
    const int lrow = lane & 15, lg = lane >> 4;

    float bj1[8], bj2[8], gj[8], bb[8];
#pragma unroll
    for (int t = 0; t < 8; ++t) {
        bj1[t] = b1[t * 16 + lrow];
        bj2[t] = b2[t * 16 + lrow];
        gj[t] = gam[t * 16 + lrow];
        bb[t] = bet[t * 16 + lrow];
    }

    for (int chunk = blockIdx.x; chunk < NCHUNK; chunk += gridDim.x) {
        const int r0 = chunk * 64 + wave * 16;
        const int arow = r0 + lrow;
        const bool rowok = arow < NN;

        v4f acc[8];
#pragma unroll
        for (int t = 0; t < 8; ++t) acc[t] = (v4f){0.f, 0.f, 0.f, 0.f};
#pragma unroll
        for (int s = 0; s < 4; ++s) {
            v8bf a = rowok ? *(const v8bf*)&hin[(size_t)arow * HD + s * 32 + lg * 8] : zero8();
#pragma unroll
            for (int t = 0; t < 8; ++t) {
                int j = t * 16 + lrow;
                v8bf b = *(const v8bf*)&lw[0][j * 128 + (((s * 4 + lg) ^ (j & 15)) << 3)];
                acc[t] = __builtin_amdgcn_mfma_f32_16x16x32_bf16(a, b, acc[t], 0, 0, 0);
            }
        }
#pragma unroll
        for (int t = 0; t < 8; ++t) {
#pragma unroll
            for (int r = 0; r < 4; ++r) {
                float v = fmaxf(acc[t][r] + bj1[t], 0.f);
                int i = lg * 4 + r;
                int k2 = t * 16 + lrow;
                lT[wave][i * 128 + (((k2 >> 3) ^ i) << 3) + (k2 & 7)] = (bf16)v;
            }
        }
        v4f acc2[8];
#pragma unroll
        for (int t = 0; t < 8; ++t) acc2[t] = (v4f){0.f, 0.f, 0.f, 0.f};
#pragma unroll
        for (int s = 0; s < 4; ++s) {
            v8bf a = *(const v8bf*)&lT[wave][lrow * 128 + (((s * 4 + lg) ^ lrow) << 3)];
#pragma unroll
            for (int t = 0; t < 8; ++t) {
                int j = t * 16 + lrow;
                v8bf b = *(const v8bf*)&lw[1][j * 128 + (((s * 4 + lg) ^ (j & 15)) << 3)];
                acc2[t] = __builtin_amdgcn_mfma_f32_16x16x32_bf16(a, b, acc2[t], 0, 0, 0);
            }
        }
        float vout[8][4];
#pragma unroll
        for (int t = 0; t < 8; ++t) {
#pragma unroll
            for (int r = 0; r < 4; ++r) vout[t][r] = fmaxf(acc2[t][r] + bj2[t], 0.f);
        }
        if (do_ln) {
            float s1[4] = {0.f, 0.f, 0.f, 0.f}, s2[4] = {0.f, 0.f, 0.f, 0.f};
#pragma unroll
            for (int t = 0; t < 8; ++t)
#pragma unroll
                for (int r = 0; r < 4; ++r) {
                    float v = vout[t][r];
                    s1[r] += v;
                    s2[r] += v * v;
                }
#pragma unroll
            for (int m = 1; m < 16; m <<= 1) {
#pragma unroll
                for (int r = 0; r < 4; ++r) {
                    s1[r] += __shfl_xor(s1[r], m, 64);
                    s2[r] += __shfl_xor(s2[r], m, 64);
                }
            }
#pragma unroll
            for (int t = 0; t < 8; ++t) {
#pragma unroll
                for (int r = 0; r < 4; ++r) {
                    float mu = s1[r] * (1.f / 128.f);
                    float var = s2[r] * (1.f / 128.f) - mu * mu;
                    float rs = rsqrtf(var + 1e-5f);
                    vout[t][r] = (vout[t][r] - mu) * rs * gj[t] + bb[t];
                }
            }
        }
        if (fp8out) {
            // in-wave transpose through a byte tile (stride 144 to stagger banks)
            unsigned char* bt = (unsigned char*)&lT[wave][0];
#pragma unroll
            for (int t = 0; t < 8; ++t)
#pragma unroll
                for (int r = 0; r < 4; ++r)
                    bt[(lg * 4 + r) * 144 + t * 16 + lrow] = enc_e4m3(vout[t][r]);
            int rr = lane >> 2, cc = (lane & 3) * 32;
            uint4 w0 = *(const uint4*)&bt[rr * 144 + cc];
            uint4 w1 = *(const uint4*)&bt[rr * 144 + cc + 16];
            int row = r0 + rr;
            if (row < NN) {
                *(uint4*)&h8out[(size_t)row * HD + cc] = w0;
                *(uint4*)&h8out[(size_t)row * HD + cc + 16] = w1;
            }
        } else {
#pragma unroll
            for (int t = 0; t < 8; ++t)
#pragma unroll
                for (int r = 0; r < 4; ++r) {
                    int row = r0 + lg * 4 + r;
                    if (row < NN) hout[(size_t)row * HD + t * 16 + lrow] = (bf16)vout[t][r];
                }
        }
    }
}

// ------- fused mean-pool + head: one block per graph, 256 threads -------
__global__ void poolhead_kernel(const bf16* __restrict__ h, const int* __restrict__ gstart,
                                const float* __restrict__ Wp1, const float* __restrict__ bp1,
                                const float* __restrict__ Wp2, const float* __restrict__ bp2,
                                float* __restrict__ out) {
    __shared__ float row[128];
    __shared__ float part[128];
    __shared__ float ph[256];
    __shared__ float r0s[128];
    __shared__ float r1s[128];
    int g = blockIdx.x;
    int t = threadIdx.x;
    int f = t & 127, half = t >> 7;
    int gs = gstart[g], ge = gstart[g + 1];

    float acc = 0.f;
    int n = gs + half;
#pragma unroll 1
    for (; n + 6 < ge; n += 8) {
        float a0 = (float)h[(size_t)(n + 0) * HD + f];
        float a1 = (float)h[(size_t)(n + 2) * HD + f];
        float a2 = (float)h[(size_t)(n + 4) * HD + f];
        float a3 = (float)h[(size_t)(n + 6) * HD + f];
        acc += (a0 + a1) + (a2 + a3);
    }
    for (; n < ge; n += 2) acc += (float)h[(size_t)n * HD + f];
    if (half == 1) part[f] = acc;
    __syncthreads();
    if (half == 0) row[f] = (acc + part[f]) / fmaxf((float)(ge - gs), 1.f);
    __syncthreads();

    float p = (half == 0) ? bp1[f] : 0.f;
    int k0 = half * 64;
    for (int k = k0; k < k0 + 64; ++k) p += row[k] * Wp1[k * 128 + f];
    ph[t] = p;
    __syncthreads();
    if (t < 128) {
        float pf = ph[f] + ph[128 + f];
        r0s[f] = pf * Wp2[f * 2 + 0];
        r1s[f] = pf * Wp2[f * 2 + 1];
    }
    __syncthreads();
    for (int off = 64; off > 0; off >>= 1) {
        if (t < off) {
            r0s[t] += r0s[t + off];
            r1s[t] += r1s[t + off];
        }
        __syncthreads();
    }
    if (t == 0) {
        float e0 = r0s[0] + bp2[0];
        float e1 = r1s[0] + bp2[1];
        float m = fmaxf(e0, e1);
        float lse = m + logf(expf(e0 - m) + expf(e1 - m));
        out[g * 2 + 0] = e0;
        out[g * 2 + 1] = e1;
        out[NG * 2 + g * 2 + 0] = e0 - lse;
        out[NG * 2 + g * 2 + 1] = e1 - lse;
    }
}

extern "C" void kernel_launch(void* const* d_in, const int* in_sizes, int n_in, void* d_out,
                              int out_size, void* d_ws, size_t ws_size, hipStream_t stream) {
    const float* x = (const float*)d_in[0];
    const int* ei = (const int*)d_in[1];  // [2][E]: src row then dst row
    const int* batch = (const int*)d_in[2];
    const float* W1[3] = {(const float*)d_in[3], (const float*)d_in[7], (const float*)d_in[11]};
    const float* B1[3] = {(const float*)d_in[4], (const float*)d_in[8], (const float*)d_in[12]};
    const float* W2[3] = {(const float*)d_in[5], (const float*)d_in[9], (const float*)d_in[13]};
    const float* B2[3] = {(const float*)d_in[6], (const float*)d_in[10], (const float*)d_in[14]};
    const float* GAM[2] = {(const float*)d_in[15], (const float*)d_in[17]};
    const float* BET[2] = {(const float*)d_in[16], (const float*)d_in[18]};
    const float* Wp1 = (const float*)d_in[19];
    const float* bp1 = (const float*)d_in[20];
    const float* Wp2 = (const float*)d_in[21];
    const float* bp2 = (const float*)d_in[22];

    char* w = (char*)d_ws;
    auto alloc = [&](size_t bytes) {
        void* p = (void*)w;
        w += (bytes + 255) & ~(size_t)255;
        return p;
    };
    int* rowStart = (int*)alloc((NN + 1) * 4);
    int* cnt = (int*)alloc(NN * 4);
    int* cursor = (int*)alloc(NN * 4);
    int* part = (int*)alloc(128 * 4);
    int* gstart = (int*)alloc((NG + 1) * 4);
    bf16* Wt = (bf16*)alloc(6 * 16384 * 2);
    int* sortedSrc = (int*)alloc((size_t)NE * 4);
    unsigned char* xb8 = (unsigned char*)alloc((size_t)NN * HD);
    unsigned char* h8a = (unsigned char*)alloc((size_t)NN * HD);
    unsigned char* h8b = (unsigned char*)alloc((size_t)NN * HD);
    bf16* bufT = (bf16*)alloc((size_t)NN * HD * 2);
    bf16* bufH = (bf16*)alloc((size_t)NN * HD * 2);

    const int* srcIdx = ei;
    const int* dstIdx = ei + NE;

    // prep: conv(fp8) + zero(cnt) + bounds + all weight preps
    prep_kernel<<<PREP_TOTAL, 256, 0, stream>>>(x, xb8, cnt, batch, gstart, W1[0], W2[0], W1[1],
                                                W2[1], W1[2], W2[2], Wt);
    // CSR build
    hist_kernel<<<(NE + 255) / 256, 256, 0, stream>>>(dstIdx, cnt);
    scan_part<<<NB, 256, 0, stream>>>(cnt, part);
    scan_write<<<NB, 256, 0, stream>>>(cnt, part, rowStart, cursor);
    scatter_kernel<<<(NE + 255) / 256, 256, 0, stream>>>(srcIdx, dstIdx, cursor, sortedSrc);

    // layers: fp8 gather (HW decode, 8-lane groups) + persistent MFMA MLP
    const unsigned char* h8in[3] = {xb8, h8a, h8b};
    unsigned char* h8out[3] = {h8a, h8b, nullptr};
    for (int l = 0; l < 3; ++l) {
        agg_kernel<<<(NN * 8 + 255) / 256, 256, 0, stream>>>(h8in[l], rowStart, sortedSrc,
                                                             bufT);
        int doln = (l < 2) ? 1 : 0;
        int fp8o = (l < 2) ? 1 : 0;
        const float* g = (l < 2) ? GAM[l] : GAM[0];
        const float* be = (l < 2) ? BET[l] : BET[0];
        mlp_bf16<<<512, 256, 0, stream>>>(bufT, Wt + (size_t)(2 * l) * 16384, B1[l],
                                          Wt + (size_t)(2 * l + 1) * 16384, B2[l], g, be, doln,
                                          fp8o, h8out[l], bufH);
    }

    // fused pooling + head
    poolhead_kernel<<<NG, 256, 0, stream>>>(bufH, gstart, Wp1, bp1, Wp2, bp2, (float*)d_out);
}

// Round 12
// 213.670 us; speedup vs baseline: 1.0348x; 1.0348x over previous
//
#include <hip/hip_runtime.h>
#include <hip/hip_bf16.h>
#include <hip/hip_fp8.h>

typedef __bf16 bf16;
typedef __bf16 v8bf __attribute__((ext_vector_type(8)));
typedef float v4f __attribute__((ext_vector_type(4)));
typedef float v2f __attribute__((ext_vector_type(2)));

#define NN 100000
#define NE 600000
#define HD 128
#define NG 256
#define NB 98                    // ceil(NN/1024)
#define NCHUNK ((NN + 63) / 64)  // 1563

#define PREP_CONV 6250
#define PREP_ZERO 391
#define PREP_BNDS 391
#define PREP_W 48
#define PREP_TOTAL (PREP_CONV + PREP_ZERO + PREP_BNDS + PREP_W)  // 7080

static __device__ inline v8bf zero8() {
    v8bf z;
#pragma unroll
    for (int i = 0; i < 8; ++i) z[i] = (bf16)0.f;
    return z;
}

// ---- OCP e4m3 helpers ----
static __device__ inline unsigned char enc_e4m3(float f) {
    __hip_fp8_e4m3 q(f);
    return (unsigned char)q.__x;
}

#if __has_builtin(__builtin_amdgcn_cvt_pk_fp8_f32)
static __device__ inline unsigned int pack4_e4m3(float v0, float v1, float v2, float v3) {
    int r = 0;
    r = __builtin_amdgcn_cvt_pk_fp8_f32(v0, v1, r, false);
    r = __builtin_amdgcn_cvt_pk_fp8_f32(v2, v3, r, true);
    return (unsigned int)r;
}
#else
static __device__ inline unsigned int pack4_e4m3(float v0, float v1, float v2, float v3) {
    return (unsigned int)enc_e4m3(v0) | ((unsigned int)enc_e4m3(v1) << 8) |
           ((unsigned int)enc_e4m3(v2) << 16) | ((unsigned int)enc_e4m3(v3) << 24);
}
#endif

#if __has_builtin(__builtin_amdgcn_cvt_pk_f32_fp8)
static __device__ inline void acc8(float* a, unsigned int lo, unsigned int hi) {
    v2f p0 = __builtin_amdgcn_cvt_pk_f32_fp8((int)lo, false);
    v2f p1 = __builtin_amdgcn_cvt_pk_f32_fp8((int)lo, true);
    v2f p2 = __builtin_amdgcn_cvt_pk_f32_fp8((int)hi, false);
    v2f p3 = __builtin_amdgcn_cvt_pk_f32_fp8((int)hi, true);
    a[0] += p0.x;
    a[1] += p0.y;
    a[2] += p1.x;
    a[3] += p1.y;
    a[4] += p2.x;
    a[5] += p2.y;
    a[6] += p3.x;
    a[7] += p3.y;
}
static __device__ inline v8bf dec8_bf16(unsigned int lo, unsigned int hi) {
    v2f p0 = __builtin_amdgcn_cvt_pk_f32_fp8((int)lo, false);
    v2f p1 = __builtin_amdgcn_cvt_pk_f32_fp8((int)lo, true);
    v2f p2 = __builtin_amdgcn_cvt_pk_f32_fp8((int)hi, false);
    v2f p3 = __builtin_amdgcn_cvt_pk_f32_fp8((int)hi, true);
    v8bf o;
    o[0] = (bf16)p0.x;
    o[1] = (bf16)p0.y;
    o[2] = (bf16)p1.x;
    o[3] = (bf16)p1.y;
    o[4] = (bf16)p2.x;
    o[5] = (bf16)p2.y;
    o[6] = (bf16)p3.x;
    o[7] = (bf16)p3.y;
    return o;
}
#else
static __device__ inline float dec_e4m3(unsigned int b) {
    unsigned int e = (b >> 3) & 15u, m = b & 7u;
    unsigned int s = (b & 0x80u) << 24;
    float nv = __uint_as_float(s | ((e + 120u) << 23) | (m << 20));
    float dv = __uint_as_float(s | 0x3B000000u) * (float)(int)m;
    return e ? nv : dv;
}
static __device__ inline void acc8(float* a, unsigned int lo, unsigned int hi) {
#pragma unroll
    for (int q = 0; q < 4; ++q) a[q] += dec_e4m3((lo >> (q * 8)) & 255u);
#pragma unroll
    for (int q = 0; q < 4; ++q) a[4 + q] += dec_e4m3((hi >> (q * 8)) & 255u);
}
static __device__ inline v8bf dec8_bf16(unsigned int lo, unsigned int hi) {
    v8bf o;
#pragma unroll
    for (int q = 0; q < 4; ++q) o[q] = (bf16)dec_e4m3((lo >> (q * 8)) & 255u);
#pragma unroll
    for (int q = 0; q < 4; ++q) o[4 + q] = (bf16)dec_e4m3((hi >> (q * 8)) & 255u);
    return o;
}
#endif

// ---- prep: conv(x->fp8) | zero cnt | graph bounds | weight prep (all 6) ----
__global__ void prep_kernel(const float* __restrict__ x, unsigned char* __restrict__ xb8,
                            int* __restrict__ cnt, const int* __restrict__ batch,
                            int* __restrict__ gstart, const float* __restrict__ w10,
                            const float* __restrict__ w20, const float* __restrict__ w11,
                            const float* __restrict__ w21, const float* __restrict__ w12,
                            const float* __restrict__ w22, bf16* __restrict__ Wt) {
    int bid = blockIdx.x, tid = threadIdx.x;
    if (bid < PREP_CONV) {
        int i = bid * 256 + tid;  // one per 8 elems
        const v4f a = *(const v4f*)&x[(size_t)i * 8];
        const v4f b = *(const v4f*)&x[(size_t)i * 8 + 4];
        unsigned int r0 = pack4_e4m3(a[0], a[1], a[2], a[3]);
        unsigned int r1 = pack4_e4m3(b[0], b[1], b[2], b[3]);
        *(uint2*)&xb8[(size_t)i * 8] = make_uint2(r0, r1);
    } else if (bid < PREP_CONV + PREP_ZERO) {
        int i = (bid - PREP_CONV) * 256 + tid;
        if (i < NN) cnt[i] = 0;
    } else if (bid < PREP_CONV + PREP_ZERO + PREP_BNDS) {
        int n = (bid - PREP_CONV - PREP_ZERO) * 256 + tid;
        if (n < NN) {
            int b = batch[n];
            int prev = (n == 0) ? -1 : batch[n - 1];
            for (int g = prev + 1; g <= b; ++g) gstart[g] = n;
            if (n == NN - 1)
                for (int g = b + 1; g <= NG; ++g) gstart[g] = NN;
        }
    } else {
        int wb = bid - (PREP_CONV + PREP_ZERO + PREP_BNDS);  // 0..47
        int widx = wb >> 3;
        const float* W;
        switch (widx) {
            case 0: W = w10; break;
            case 1: W = w20; break;
            case 2: W = w11; break;
            case 3: W = w21; break;
            case 4: W = w12; break;
            default: W = w22; break;
        }
        bf16* dst = Wt + (size_t)widx * 16384;
        int c = (wb & 7) * 256 + tid;  // 0..2047
        int j = c >> 4, ck = c & 15;
        v8bf o;
#pragma unroll
        for (int q = 0; q < 8; ++q) o[q] = (bf16)W[(ck * 8 + q) * 128 + j];
        *(v8bf*)&dst[j * 128 + ((ck ^ (j & 15)) << 3)] = o;
    }
}

// ---------------- CSR build (measured-good R6 chain) ----------------
__global__ void hist_kernel(const int* __restrict__ dst, int* __restrict__ cnt) {
    int e = blockIdx.x * blockDim.x + threadIdx.x;
    if (e < NE) atomicAdd(&cnt[dst[e]], 1);
}

__global__ void scan_part(const int* __restrict__ cnt, int* __restrict__ part) {
    __shared__ int red[256];
    int b = blockIdx.x, t = threadIdx.x;
    int base = b * 1024 + t * 4;
    int s = 0;
#pragma unroll
    for (int q = 0; q < 4; ++q) {
        int i = base + q;
        s += (i < NN) ? cnt[i] : 0;
    }
    red[t] = s;
    __syncthreads();
    for (int off = 128; off > 0; off >>= 1) {
        if (t < off) red[t] += red[t + off];
        __syncthreads();
    }
    if (t == 0) part[b] = red[0];
}

__global__ void scan_write(const int* __restrict__ cnt, const int* __restrict__ part,
                           int* __restrict__ rowStart, int* __restrict__ cursor) {
    __shared__ int tsum[256];
    __shared__ int psc[128];
    int b = blockIdx.x, t = threadIdx.x;
    if (t < 128) psc[t] = (t < NB) ? part[t] : 0;
    __syncthreads();
    for (int off = 1; off < 128; off <<= 1) {
        int v = (t < 128 && t >= off) ? psc[t - off] : 0;
        __syncthreads();
        if (t < 128) psc[t] += v;
        __syncthreads();
    }
    int blockoff = (b == 0) ? 0 : psc[b - 1];

    int base = b * 1024 + t * 4;
    int v[4];
    int s = 0;
#pragma unroll
    for (int q = 0; q < 4; ++q) {
        int i = base + q;
        v[q] = (i < NN) ? cnt[i] : 0;
        s += v[q];
    }
    tsum[t] = s;
    __syncthreads();
    for (int off = 1; off < 256; off <<= 1) {
        int x = (t >= off) ? tsum[t - off] : 0;
        __syncthreads();
        tsum[t] += x;
        __syncthreads();
    }
    int excl = tsum[t] - s + blockoff;
#pragma unroll
    for (int q = 0; q < 4; ++q) {
        int i = base + q;
        if (i < NN) {
            rowStart[i] = excl;
            cursor[i] = excl;
            excl += v[q];
        }
    }
    if (b == 0 && t == 0) rowStart[NN] = NE;
}

__global__ void scatter_kernel(const int* __restrict__ src, const int* __restrict__ dst,
                               int* __restrict__ cursor, int* __restrict__ sortedSrc) {
    int e = blockIdx.x * blockDim.x + threadIdx.x;
    if (e < NE) {
        int d = dst[e];
        int pos = atomicAdd(&cursor[d], 1);
        sortedSrc[pos] = src[e];
    }
}

// ------- aggregation from fp8: bufT8 = enc(dec(h8[node]) + sum dec(h8[src])) -------
// 4 nodes per wave (16 lanes x 8B per row, R10-best grouping); 4-deep pipelined
// gather; HW cvt_pk decode; fp8 output (halves agg-write + mlp-read traffic).
__global__ __launch_bounds__(256) void agg_kernel(const unsigned char* __restrict__ h8,
                                                  const int* __restrict__ rowStart,
                                                  const int* __restrict__ sortedSrc,
                                                  unsigned char* __restrict__ hin8) {
    int node = (blockIdx.x * blockDim.x + threadIdx.x) >> 4;
    if (node >= NN) return;
    int l16 = threadIdx.x & 15;
    int grp = (threadIdx.x & 63) >> 4;
    int s = rowStart[node], e = rowStart[node + 1];
    float a[8] = {0.f, 0.f, 0.f, 0.f, 0.f, 0.f, 0.f, 0.f};
    uint2 self = *(const uint2*)&h8[(size_t)node * HD + l16 * 8];
    acc8(a, self.x, self.y);
    for (int base = s; base < e; base += 16) {
        int cnt = e - base;
        if (cnt > 16) cnt = 16;
        int idx = (l16 < cnt) ? sortedSrc[base + l16] : 0;
        int i = 0;
        for (; i + 4 <= cnt; i += 4) {
            int sn0 = __shfl(idx, grp * 16 + i + 0, 64);
            int sn1 = __shfl(idx, grp * 16 + i + 1, 64);
            int sn2 = __shfl(idx, grp * 16 + i + 2, 64);
            int sn3 = __shfl(idx, grp * 16 + i + 3, 64);
            uint2 x0 = *(const uint2*)&h8[(size_t)sn0 * HD + l16 * 8];
            uint2 x1 = *(const uint2*)&h8[(size_t)sn1 * HD + l16 * 8];
            uint2 x2 = *(const uint2*)&h8[(size_t)sn2 * HD + l16 * 8];
            uint2 x3 = *(const uint2*)&h8[(size_t)sn3 * HD + l16 * 8];
            acc8(a, x0.x, x0.y);
            acc8(a, x1.x, x1.y);
            acc8(a, x2.x, x2.y);
            acc8(a, x3.x, x3.y);
        }
        for (; i + 2 <= cnt; i += 2) {
            int sn0 = __shfl(idx, grp * 16 + i + 0, 64);
            int sn1 = __shfl(idx, grp * 16 + i + 1, 64);
            uint2 x0 = *(const uint2*)&h8[(size_t)sn0 * HD + l16 * 8];
            uint2 x1 = *(const uint2*)&h8[(size_t)sn1 * HD + l16 * 8];
            acc8(a, x0.x, x0.y);
            acc8(a, x1.x, x1.y);
        }
        if (i < cnt) {
            int sn0 = __shfl(idx, grp * 16 + i, 64);
            uint2 x0 = *(const uint2*)&h8[(size_t)sn0 * HD + l16 * 8];
            acc8(a, x0.x, x0.y);
        }
    }
    unsigned int r0 = pack4_e4m3(a[0], a[1], a[2], a[3]);
    unsigned int r1 = pack4_e4m3(a[4], a[5], a[6], a[7]);
    *(uint2*)&hin8[(size_t)node * HD + l16 * 8] = make_uint2(r0, r1);
}

// -------- fused MLP: persistent blocks, weights staged once in LDS --------
// A-operand read as fp8, decoded in-register to bf16 fragments.
// fp8out=1 (layers 0,1): emit fp8 h_out via in-wave LDS byte-tile transpose.
// fp8out=0 (layer 2): emit bf16 h_out for pooling.
__global__ __launch_bounds__(256) void mlp_bf16(
    const unsigned char* __restrict__ hin8, const bf16* __restrict__ W1s,
    const float* __restrict__ b1, const bf16* __restrict__ W2s, const float* __restrict__ b2,
    const float* __restrict__ gam, const float* __restrict__ bet, const int do_ln,
    const int fp8out, unsigned char* __restrict__ h8out, bf16* __restrict__ hout) {
    __shared__ bf16 lw[2][128 * 128];  // swizzled W1^T, W2^T (64KB)
    __shared__ bf16 lT[4][16 * 128];   // per-wave: relu tile, then fp8 byte-tile (16KB)

    const int tid = threadIdx.x;
    for (int i = tid; i < 2048; i += 256) {
        *(v8bf*)&lw[0][i * 8] = *(const v8bf*)&W1s[i * 8];
        *(v8bf*)&lw[1][i * 8] = *(const v8bf*)&W2s[i * 8];
    }
    __syncthreads();

    const int wave = tid >> 6, lane = tid & 63;
    const int lrow = lane & 15, lg = lane >> 4;

    float bj1[8], bj2[8], gj[8], bb[8];
#pragma unroll
    for (int t = 0; t < 8; ++t) {
        bj1[t] = b1[t * 16 + lrow];
        bj2[t] = b2[t * 16 + lrow];
        gj[t] = gam[t * 16 + lrow];
        bb[t] = bet[t * 16 + lrow];
    }

    for (int chunk = blockIdx.x; chunk < NCHUNK; chunk += gridDim.x) {
        const int r0 = chunk * 64 + wave * 16;
        const int arow = r0 + lrow;
        const bool rowok = arow < NN;

        v4f acc[8];
#pragma unroll
        for (int t = 0; t < 8; ++t) acc[t] = (v4f){0.f, 0.f, 0.f, 0.f};
#pragma unroll
        for (int s = 0; s < 4; ++s) {
            v8bf a;
            if (rowok) {
                uint2 raw = *(const uint2*)&hin8[(size_t)arow * HD + s * 32 + lg * 8];
                a = dec8_bf16(raw.x, raw.y);
            } else {
                a = zero8();
            }
#pragma unroll
            for (int t = 0; t < 8; ++t) {
                int j = t * 16 + lrow;
                v8bf b = *(const v8bf*)&lw[0][j * 128 + (((s * 4 + lg) ^ (j & 15)) << 3)];
                acc[t] = __builtin_amdgcn_mfma_f32_16x16x32_bf16(a, b, acc[t], 0, 0, 0);
            }
        }
#pragma unroll
        for (int t = 0; t < 8; ++t) {
#pragma unroll
            for (int r = 0; r < 4; ++r) {
                float v = fmaxf(acc[t][r] + bj1[t], 0.f);
                int i = lg * 4 + r;
                int k2 = t * 16 + lrow;
                lT[wave][i * 128 + (((k2 >> 3) ^ i) << 3) + (k2 & 7)] = (bf16)v;
            }
        }
        v4f acc2[8];
#pragma unroll
        for (int t = 0; t < 8; ++t) acc2[t] = (v4f){0.f, 0.f, 0.f, 0.f};
#pragma unroll
        for (int s = 0; s < 4; ++s) {
            v8bf a = *(const v8bf*)&lT[wave][lrow * 128 + (((s * 4 + lg) ^ lrow) << 3)];
#pragma unroll
            for (int t = 0; t < 8; ++t) {
                int j = t * 16 + lrow;
                v8bf b = *(const v8bf*)&lw[1][j * 128 + (((s * 4 + lg) ^ (j & 15)) << 3)];
                acc2[t] = __builtin_amdgcn_mfma_f32_16x16x32_bf16(a, b, acc2[t], 0, 0, 0);
            }
        }
        float vout[8][4];
#pragma unroll
        for (int t = 0; t < 8; ++t) {
#pragma unroll
            for (int r = 0; r < 4; ++r) vout[t][r] = fmaxf(acc2[t][r] + bj2[t], 0.f);
        }
        if (do_ln) {
            float s1[4] = {0.f, 0.f, 0.f, 0.f}, s2[4] = {0.f, 0.f, 0.f, 0.f};
#pragma unroll
            for (int t = 0; t < 8; ++t)
#pragma unroll
                for (int r = 0; r < 4; ++r) {
                    float v = vout[t][r];
                    s1[r] += v;
                    s2[r] += v * v;
                }
#pragma unroll
            for (int m = 1; m < 16; m <<= 1) {
#pragma unroll
                for (int r = 0; r < 4; ++r) {
                    s1[r] += __shfl_xor(s1[r], m, 64);
                    s2[r] += __shfl_xor(s2[r], m, 64);
                }
            }
#pragma unroll
            for (int t = 0; t < 8; ++t) {
#pragma unroll
                for (int r = 0; r < 4; ++r) {
                    float mu = s1[r] * (1.f / 128.f);
                    float var = s2[r] * (1.f / 128.f) - mu * mu;
                    float rs = rsqrtf(var + 1e-5f);
                    vout[t][r] = (vout[t][r] - mu) * rs * gj[t] + bb[t];
                }
            }
        }
        if (fp8out) {
            // in-wave transpose through a byte tile (stride 144 to stagger banks)
            unsigned char* bt = (unsigned char*)&lT[wave][0];
#pragma unroll
            for (int t = 0; t < 8; ++t)
#pragma unroll
                for (int r = 0; r < 4; ++r)
                    bt[(lg * 4 + r) * 144 + t * 16 + lrow] = enc_e4m3(vout[t][r]);
            int rr = lane >> 2, cc = (lane & 3) * 32;
            uint4 w0 = *(const uint4*)&bt[rr * 144 + cc];
            uint4 w1 = *(const uint4*)&bt[rr * 144 + cc + 16];
            int row = r0 + rr;
            if (row < NN) {
                *(uint4*)&h8out[(size_t)row * HD + cc] = w0;
                *(uint4*)&h8out[(size_t)row * HD + cc + 16] = w1;
            }
        } else {
#pragma unroll
            for (int t = 0; t < 8; ++t)
#pragma unroll
                for (int r = 0; r < 4; ++r) {
                    int row = r0 + lg * 4 + r;
                    if (row < NN) hout[(size_t)row * HD + t * 16 + lrow] = (bf16)vout[t][r];
                }
        }
    }
}

// ------- fused mean-pool + head: one block per graph, 256 threads -------
__global__ void poolhead_kernel(const bf16* __restrict__ h, const int* __restrict__ gstart,
                                const float* __restrict__ Wp1, const float* __restrict__ bp1,
                                const float* __restrict__ Wp2, const float* __restrict__ bp2,
                                float* __restrict__ out) {
    __shared__ float row[128];
    __shared__ float part[128];
    __shared__ float ph[256];
    __shared__ float r0s[128];
    __shared__ float r1s[128];
    int g = blockIdx.x;
    int t = threadIdx.x;
    int f = t & 127, half = t >> 7;
    int gs = gstart[g], ge = gstart[g + 1];

    float acc = 0.f;
    int n = gs + half;
#pragma unroll 1
    for (; n + 6 < ge; n += 8) {
        float a0 = (float)h[(size_t)(n + 0) * HD + f];
        float a1 = (float)h[(size_t)(n + 2) * HD + f];
        float a2 = (float)h[(size_t)(n + 4) * HD + f];
        float a3 = (float)h[(size_t)(n + 6) * HD + f];
        acc += (a0 + a1) + (a2 + a3);
    }
    for (; n < ge; n += 2) acc += (float)h[(size_t)n * HD + f];
    if (half == 1) part[f] = acc;
    __syncthreads();
    if (half == 0) row[f] = (acc + part[f]) / fmaxf((float)(ge - gs), 1.f);
    __syncthreads();

    float p = (half == 0) ? bp1[f] : 0.f;
    int k0 = half * 64;
    for (int k = k0; k < k0 + 64; ++k) p += row[k] * Wp1[k * 128 + f];
    ph[t] = p;
    __syncthreads();
    if (t < 128) {
        float pf = ph[f] + ph[128 + f];
        r0s[f] = pf * Wp2[f * 2 + 0];
        r1s[f] = pf * Wp2[f * 2 + 1];
    }
    __syncthreads();
    for (int off = 64; off > 0; off >>= 1) {
        if (t < off) {
            r0s[t] += r0s[t + off];
            r1s[t] += r1s[t + off];
        }
        __syncthreads();
    }
    if (t == 0) {
        float e0 = r0s[0] + bp2[0];
        float e1 = r1s[0] + bp2[1];
        float m = fmaxf(e0, e1);
        float lse = m + logf(expf(e0 - m) + expf(e1 - m));
        out[g * 2 + 0] = e0;
        out[g * 2 + 1] = e1;
        out[NG * 2 + g * 2 + 0] = e0 - lse;
        out[NG * 2 + g * 2 + 1] = e1 - lse;
    }
}

extern "C" void kernel_launch(void* const* d_in, const int* in_sizes, int n_in, void* d_out,
                              int out_size, void* d_ws, size_t ws_size, hipStream_t stream) {
    const float* x = (const float*)d_in[0];
    const int* ei = (const int*)d_in[1];  // [2][E]: src row then dst row
    const int* batch = (const int*)d_in[2];
    const float* W1[3] = {(const float*)d_in[3], (const float*)d_in[7], (const float*)d_in[11]};
    const float* B1[3] = {(const float*)d_in[4], (const float*)d_in[8], (const float*)d_in[12]};
    const float* W2[3] = {(const float*)d_in[5], (const float*)d_in[9], (const float*)d_in[13]};
    const float* B2[3] = {(const float*)d_in[6], (const float*)d_in[10], (const float*)d_in[14]};
    const float* GAM[2] = {(const float*)d_in[15], (const float*)d_in[17]};
    const float* BET[2] = {(const float*)d_in[16], (const float*)d_in[18]};
    const float* Wp1 = (const float*)d_in[19];
    const float* bp1 = (const float*)d_in[20];
    const float* Wp2 = (const float*)d_in[21];
    const float* bp2 = (const float*)d_in[22];

    char* w = (char*)d_ws;
    auto alloc = [&](size_t bytes) {
        void* p = (void*)w;
        w += (bytes + 255) & ~(size_t)255;
        return p;
    };
    int* rowStart = (int*)alloc((NN + 1) * 4);
    int* cnt = (int*)alloc(NN * 4);
    int* cursor = (int*)alloc(NN * 4);
    int* part = (int*)alloc(128 * 4);
    int* gstart = (int*)alloc((NG + 1) * 4);
    bf16* Wt = (bf16*)alloc(6 * 16384 * 2);
    int* sortedSrc = (int*)alloc((size_t)NE * 4);
    unsigned char* xb8 = (unsigned char*)alloc((size_t)NN * HD);
    unsigned char* h8a = (unsigned char*)alloc((size_t)NN * HD);
    unsigned char* h8b = (unsigned char*)alloc((size_t)NN * HD);
    unsigned char* bufT8 = (unsigned char*)alloc((size_t)NN * HD);
    bf16* bufH = (bf16*)alloc((size_t)NN * HD * 2);

    const int* srcIdx = ei;
    const int* dstIdx = ei + NE;

    // prep: conv(fp8) + zero(cnt) + bounds + all weight preps
    prep_kernel<<<PREP_TOTAL, 256, 0, stream>>>(x, xb8, cnt, batch, gstart, W1[0], W2[0], W1[1],
                                                W2[1], W1[2], W2[2], Wt);
    // CSR build
    hist_kernel<<<(NE + 255) / 256, 256, 0, stream>>>(dstIdx, cnt);
    scan_part<<<NB, 256, 0, stream>>>(cnt, part);
    scan_write<<<NB, 256, 0, stream>>>(cnt, part, rowStart, cursor);
    scatter_kernel<<<(NE + 255) / 256, 256, 0, stream>>>(srcIdx, dstIdx, cursor, sortedSrc);

    // layers: fp8 gather (HW decode) + persistent MFMA MLP (fp8 A-operand)
    const unsigned char* h8in[3] = {xb8, h8a, h8b};
    unsigned char* h8out[3] = {h8a, h8b, nullptr};
    for (int l = 0; l < 3; ++l) {
        agg_kernel<<<(NN * 16 + 255) / 256, 256, 0, stream>>>(h8in[l], rowStart, sortedSrc,
                                                              bufT8);
        int doln = (l < 2) ? 1 : 0;
        int fp8o = (l < 2) ? 1 : 0;
        const float* g = (l < 2) ? GAM[l] : GAM[0];
        const float* be = (l < 2) ? BET[l] : BET[0];
        mlp_bf16<<<512, 256, 0, stream>>>(bufT8, Wt + (size_t)(2 * l) * 16384, B1[l],
                                          Wt + (size_t)(2 * l + 1) * 16384, B2[l], g, be, doln,
                                          fp8o, h8out[l], bufH);
    }

    // fused pooling + head
    poolhead_kernel<<<NG, 256, 0, stream>>>(bufH, gstart, Wp1, bp1, Wp2, bp2, (float*)d_out);
}